// Round 2
// baseline (745.941 us; speedup 1.0000x reference)
//
#include <hip/hip_runtime.h>
#include <math.h>
#include <stdint.h>

#define DEV __device__ __forceinline__

typedef __attribute__((ext_vector_type(8))) short bf16x8;
typedef __attribute__((ext_vector_type(4))) float f32x4;
typedef __attribute__((ext_vector_type(4))) int i32x4;
typedef unsigned short u16;
typedef unsigned int u32;

constexpr int cB = 8, cN = 1024, cD = 1024, cH = 16, cF = 4096, cHD = 64;
constexpr int BH = cB * cH;    // 128
constexpr int TOK = cB * cN;   // 8192

DEV u16 f2bf(float f) {
  u32 x = __float_as_uint(f);
  u32 r = (x + 0x7fffu + ((x >> 16) & 1u)) >> 16;
  return (u16)r;
}

DEV void gl_lds16(const u16* g, u16* l) {
  __builtin_amdgcn_global_load_lds((const __attribute__((address_space(1))) u32*)g,
                                   (__attribute__((address_space(3))) u32*)l, 16, 0, 0);
}

// ---------------- mask normalize (bool-byte, int32, or f32 mask) ---------------
__global__ void mask_norm(const unsigned char* __restrict__ rawb, int* __restrict__ keep) {
  const u32* rawi = (const u32*)rawb;
  const float* rawf = (const float*)rawb;
  int t = threadIdx.x;  // 1024 threads, 1 block
  int fb = 0, ff = 0;
  for (int i = t; i < 2048; i += 1024) {
    u32 wv = rawi[i];
    if (wv == 0x3f800000u) ff = 1;
    else if (wv > 1u) fb = 1;
  }
  __shared__ int sf[2];
  if (t == 0) { sf[0] = 0; sf[1] = 0; }
  __syncthreads();
  if (fb) atomicOr(&sf[0], 1);
  if (ff) atomicOr(&sf[1], 1);
  __syncthreads();
  const int isf32 = sf[1];
  const int isbool = sf[0] && !isf32;
  for (int i = t; i < TOK; i += 1024)
    keep[i] = isf32 ? (rawf[i] != 0.f) : (isbool ? (rawb[i] != 0) : (rawi[i] != 0u));
}

// ---------------- f32 -> bf16 convert ------------------------------------------
__global__ void cvt_k(const float* __restrict__ in, u16* __restrict__ out, int n4) {
  int i = blockIdx.x * blockDim.x + threadIdx.x;
  if (i >= n4) return;
  float4 v = ((const float4*)in)[i];
  short4 o;
  o.x = (short)f2bf(v.x); o.y = (short)f2bf(v.y);
  o.z = (short)f2bf(v.z); o.w = (short)f2bf(v.w);
  ((short4*)out)[i] = o;
}

// ---------------- LayerNorm (1024 cols, 256 threads/row) -----------------------
template <int WF32>
__global__ __launch_bounds__(256) void ln_k(const float* __restrict__ in,
                                            const float* __restrict__ g,
                                            const float* __restrict__ be,
                                            u16* __restrict__ outb,
                                            float* __restrict__ outf) {
  const int row = blockIdx.x;
  const int t = threadIdx.x;
  const float4 v = ((const float4*)(in + (size_t)row * cD))[t];
  float s = v.x + v.y + v.z + v.w;
  float s2 = v.x * v.x + v.y * v.y + v.z * v.z + v.w * v.w;
#pragma unroll
  for (int m = 1; m < 64; m <<= 1) {
    s += __shfl_xor(s, m);
    s2 += __shfl_xor(s2, m);
  }
  __shared__ float ls[8];
  const int w = t >> 6;
  if ((t & 63) == 0) { ls[w] = s; ls[4 + w] = s2; }
  __syncthreads();
  s = ls[0] + ls[1] + ls[2] + ls[3];
  s2 = ls[4] + ls[5] + ls[6] + ls[7];
  const float mean = s * (1.f / cD);
  const float var = fmaxf(s2 * (1.f / cD) - mean * mean, 0.f);
  const float inv = rsqrtf(var + 1e-5f);
  const float4 gg = ((const float4*)g)[t];
  const float4 bb = ((const float4*)be)[t];
  const float o0 = (v.x - mean) * inv * gg.x + bb.x;
  const float o1 = (v.y - mean) * inv * gg.y + bb.y;
  const float o2 = (v.z - mean) * inv * gg.z + bb.z;
  const float o3 = (v.w - mean) * inv * gg.w + bb.w;
  short4 ob;
  ob.x = (short)f2bf(o0); ob.y = (short)f2bf(o1);
  ob.z = (short)f2bf(o2); ob.w = (short)f2bf(o3);
  ((short4*)(outb + (size_t)row * cD))[t] = ob;
  if (WF32) {
    float4 of; of.x = o0; of.y = o1; of.z = o2; of.w = o3;
    ((float4*)(outf + (size_t)row * cD))[t] = of;
  }
}

// ---------------- GEMM: C = A(MxK) * B(NxK)^T, bf16 in, fused epilogues --------
// EP 0: QKV scatter -> q/k/v (B,H,N,64) bf16
// EP 1: outf = C + bias + resid (f32)
// EP 2: ob0  = gelu(C + bias)  (bf16, row stride N)
// EP 3: outf += C + bias        (f32, accumulate into pre-filled d_out)
template <int EP>
__global__ __launch_bounds__(256) void gemm_bt(const u16* __restrict__ A,
                                               const u16* __restrict__ Bw,
                                               int M, int N, int K,
                                               const float* __restrict__ bias,
                                               const float* __restrict__ resid,
                                               float* __restrict__ outf,
                                               u16* __restrict__ ob0,
                                               u16* __restrict__ ob1,
                                               u16* __restrict__ ob2) {
  __shared__ u16 As[128 * 32];
  __shared__ u16 Bs[128 * 32];
  const int t = threadIdx.x;
  const int l = t & 63;
  const int w = t >> 6;
  const int wr = w >> 1, wc = w & 1;
  const int row0 = blockIdx.y * 128;
  const int col0 = blockIdx.x * 128;

  f32x4 acc[4][4] = {};

  // staging: thread t covers row (t>>2), cols (t&3)*8 .. +8 (16B each)
  const u16* Ag = A + (size_t)(row0 + (t >> 2)) * K + (t & 3) * 8;
  const u16* Bg = Bw + (size_t)(col0 + (t >> 2)) * K + (t & 3) * 8;
  const size_t step64 = (size_t)64 * K;
  u16* ldsA0 = As + (size_t)w * 512;
  u16* ldsA1 = As + 2048 + (size_t)w * 512;
  u16* ldsB0 = Bs + (size_t)w * 512;
  u16* ldsB1 = Bs + 2048 + (size_t)w * 512;

  const int fr = l & 15, fk = (l >> 4) * 8;

  for (int k0 = 0; k0 < K; k0 += 32) {
    gl_lds16(Ag + k0, ldsA0);
    gl_lds16(Ag + step64 + k0, ldsA1);
    gl_lds16(Bg + k0, ldsB0);
    gl_lds16(Bg + step64 + k0, ldsB1);
    __syncthreads();
    bf16x8 af[4], bf[4];
#pragma unroll
    for (int m = 0; m < 4; ++m)
      af[m] = *(const bf16x8*)&As[(wr * 64 + m * 16 + fr) * 32 + fk];
#pragma unroll
    for (int n = 0; n < 4; ++n)
      bf[n] = *(const bf16x8*)&Bs[(wc * 64 + n * 16 + fr) * 32 + fk];
#pragma unroll
    for (int m = 0; m < 4; ++m)
#pragma unroll
      for (int n = 0; n < 4; ++n)
        acc[m][n] = __builtin_amdgcn_mfma_f32_16x16x32_bf16(af[m], bf[n], acc[m][n], 0, 0, 0);
    __syncthreads();
  }

#pragma unroll
  for (int m = 0; m < 4; ++m) {
    const int grb = row0 + wr * 64 + m * 16 + (l >> 4) * 4;
#pragma unroll
    for (int n = 0; n < 4; ++n) {
      const int gc = col0 + wc * 64 + n * 16 + fr;
#pragma unroll
      for (int r = 0; r < 4; ++r) {
        const int gr = grb + r;
        const float cv = acc[m][n][r];
        if constexpr (EP == 0) {
          const int which = gc >> 10;
          const int hh = (gc >> 6) & 15;
          const int dd = gc & 63;
          const int bb = gr >> 10, nn = gr & 1023;
          u16* dst = which == 0 ? ob0 : (which == 1 ? ob1 : ob2);
          dst[(((size_t)bb * cH + hh) * cN + nn) * cHD + dd] = f2bf(cv);
        } else if constexpr (EP == 1) {
          const size_t idx = (size_t)gr * N + gc;
          outf[idx] = cv + bias[gc] + resid[idx];
        } else if constexpr (EP == 2) {
          const float u = cv + bias[gc];
          const float ge = 0.5f * u * (1.f + erff(u * 0.70710678118654752f));
          ob0[(size_t)gr * N + gc] = f2bf(ge);
        } else {
          const size_t idx = (size_t)gr * N + gc;
          outf[idx] += cv + bias[gc];
        }
      }
    }
  }
}

// ---------------- flash attention, 64 q-rows/block, 4 waves --------------------
__global__ __launch_bounds__(256) void attn_k(const u16* __restrict__ Q,
                                              const u16* __restrict__ K,
                                              const u16* __restrict__ V,
                                              const int* __restrict__ keep,
                                              u16* __restrict__ out) {
  __shared__ u16 Ks[32 * 72];
  __shared__ u16 Vt[64 * 40];
  __shared__ u16 Ps[4][16 * 40];

  const int t = threadIdx.x, l = t & 63, w = t >> 6;
  const int bh = blockIdx.x;
  const int qt = blockIdx.y;
  const int b = bh >> 4, h = bh & 15;
  const u16* Qb = Q + (size_t)bh * cN * cHD;
  const u16* Kb = K + (size_t)bh * cN * cHD;
  const u16* Vb = V + (size_t)bh * cN * cHD;
  const int fr = l & 15, fg = l >> 4;

  const int qrow = qt * 64 + w * 16;
  const bf16x8 aq0 = *(const bf16x8*)&Qb[(size_t)(qrow + fr) * cHD + fg * 8];
  const bf16x8 aq1 = *(const bf16x8*)&Qb[(size_t)(qrow + fr) * cHD + 32 + fg * 8];

  bool rkeep[4];
#pragma unroll
  for (int r = 0; r < 4; ++r) rkeep[r] = keep[b * cN + qrow + fg * 4 + r] != 0;

  float mrun[4], lrun[4];
  f32x4 o[4] = {};
#pragma unroll
  for (int r = 0; r < 4; ++r) { mrun[r] = -__builtin_inff(); lrun[r] = 0.f; }

  const int sr = t >> 3;          // 0..31
  const int scol = (t & 7) * 8;   // 0..56

  for (int kt = 0; kt < 32; ++kt) {
    {
      const size_t gsrc = (size_t)(kt * 32 + sr) * cHD + scol;
      const i32x4 kv = *(const i32x4*)&Kb[gsrc];
      const i32x4 vv = *(const i32x4*)&Vb[gsrc];
      *(i32x4*)&Ks[sr * 72 + scol] = kv;
      const u32 uu[4] = {(u32)vv.x, (u32)vv.y, (u32)vv.z, (u32)vv.w};
#pragma unroll
      for (int j = 0; j < 4; ++j) {
        Vt[(scol + 2 * j) * 40 + sr] = (u16)(uu[j] & 0xffffu);
        Vt[(scol + 2 * j + 1) * 40 + sr] = (u16)(uu[j] >> 16);
      }
    }
    __syncthreads();

    float p[2][4];
#pragma unroll
    for (int n = 0; n < 2; ++n) {
      const bf16x8 bk0 = *(const bf16x8*)&Ks[(n * 16 + fr) * 72 + fg * 8];
      const bf16x8 bk1 = *(const bf16x8*)&Ks[(n * 16 + fr) * 72 + 32 + fg * 8];
      f32x4 z = {};
      z = __builtin_amdgcn_mfma_f32_16x16x32_bf16(aq0, bk0, z, 0, 0, 0);
      z = __builtin_amdgcn_mfma_f32_16x16x32_bf16(aq1, bk1, z, 0, 0, 0);
      const int key = kt * 32 + n * 16 + fr;
      const bool ck = keep[b * cN + key] != 0;
#pragma unroll
      for (int r = 0; r < 4; ++r) {
        const float sc = z[r] * 0.125f;
        p[n][r] = (ck && rkeep[r]) ? sc : -3.402823466e38f;
      }
    }

#pragma unroll
    for (int r = 0; r < 4; ++r) {
      float tm = fmaxf(p[0][r], p[1][r]);
#pragma unroll
      for (int m = 1; m < 16; m <<= 1) tm = fmaxf(tm, __shfl_xor(tm, m));
      const float mn = fmaxf(mrun[r], tm);
      const float alpha = __expf(mrun[r] - mn);
      const float p0 = __expf(p[0][r] - mn);
      const float p1 = __expf(p[1][r] - mn);
      float ts = p0 + p1;
#pragma unroll
      for (int m = 1; m < 16; m <<= 1) ts += __shfl_xor(ts, m);
      lrun[r] = lrun[r] * alpha + ts;
      mrun[r] = mn;
#pragma unroll
      for (int n4 = 0; n4 < 4; ++n4) o[n4][r] *= alpha;
      p[0][r] = p0;
      p[1][r] = p1;
    }

#pragma unroll
    for (int r = 0; r < 4; ++r) {
      Ps[w][(fg * 4 + r) * 40 + fr] = f2bf(p[0][r]);
      Ps[w][(fg * 4 + r) * 40 + 16 + fr] = f2bf(p[1][r]);
    }
    asm volatile("s_waitcnt lgkmcnt(0)" ::: "memory");
    const bf16x8 pa = *(const bf16x8*)&Ps[w][fr * 40 + fg * 8];
#pragma unroll
    for (int n4 = 0; n4 < 4; ++n4) {
      const bf16x8 bv = *(const bf16x8*)&Vt[(n4 * 16 + fr) * 40 + fg * 8];
      o[n4] = __builtin_amdgcn_mfma_f32_16x16x32_bf16(pa, bv, o[n4], 0, 0, 0);
    }
    __syncthreads();
  }

#pragma unroll
  for (int n4 = 0; n4 < 4; ++n4) {
#pragma unroll
    for (int r = 0; r < 4; ++r) {
      const int nrow = qrow + fg * 4 + r;
      const float val = o[n4][r] / lrun[r];
      out[((size_t)b * cN + nrow) * cD + h * 64 + n4 * 16 + fr] = f2bf(val);
    }
  }
}

// ---------------- launch -------------------------------------------------------
extern "C" void kernel_launch(void* const* d_in, const int* in_sizes, int n_in,
                              void* d_out, int out_size, void* d_ws, size_t ws_size,
                              hipStream_t stream) {
  (void)in_sizes; (void)n_in; (void)out_size; (void)ws_size;
  const float* src = (const float*)d_in[0];
  const void* maskp = d_in[1];
  const float* Wqkv = (const float*)d_in[2];
  const float* Wproj = (const float*)d_in[3];
  const float* bproj = (const float*)d_in[4];
  const float* W1 = (const float*)d_in[5];
  const float* b1 = (const float*)d_in[6];
  const float* W2 = (const float*)d_in[7];
  const float* b2 = (const float*)d_in[8];
  const float* g0 = (const float*)d_in[9];
  const float* be0 = (const float*)d_in[10];
  const float* g1 = (const float*)d_in[11];
  const float* be1 = (const float*)d_in[12];
  float* out = (float*)d_out;

  char* ws = (char*)d_ws;
  size_t off = 0;
  auto alloc = [&](size_t bytes) -> char* {
    char* p = ws + off;
    off += (bytes + 255) & ~(size_t)255;
    return p;
  };
  u16* wqkv_b = (u16*)alloc((size_t)3 * cD * cD * 2);
  u16* wproj_b = (u16*)alloc((size_t)cD * cD * 2);
  u16* w1_b = (u16*)alloc((size_t)cF * cD * 2);
  u16* w2_b = (u16*)alloc((size_t)cD * cF * 2);
  u16* h_b = (u16*)alloc((size_t)TOK * cD * 2);  // reused as attnout
  u16* q_b = (u16*)alloc((size_t)TOK * cD * 2);
  u16* k_b = (u16*)alloc((size_t)TOK * cD * 2);
  u16* v_b = (u16*)alloc((size_t)TOK * cD * 2);
  float* x1 = (float*)alloc((size_t)TOK * cD * 4);
  u16* x_b = (u16*)alloc((size_t)TOK * cD * 2);
  u16* f1_b = (u16*)alloc((size_t)TOK * cF * 2);
  int* keep = (int*)alloc((size_t)TOK * 4);

  mask_norm<<<1, 1024, 0, stream>>>((const unsigned char*)maskp, keep);
  cvt_k<<<(3 * cD * cD / 4 + 255) / 256, 256, 0, stream>>>(Wqkv, wqkv_b, 3 * cD * cD / 4);
  cvt_k<<<(cD * cD / 4 + 255) / 256, 256, 0, stream>>>(Wproj, wproj_b, cD * cD / 4);
  cvt_k<<<(cF * cD / 4 + 255) / 256, 256, 0, stream>>>(W1, w1_b, cF * cD / 4);
  cvt_k<<<(cD * cF / 4 + 255) / 256, 256, 0, stream>>>(W2, w2_b, cD * cF / 4);
  ln_k<0><<<TOK, 256, 0, stream>>>(src, g0, be0, h_b, nullptr);
  gemm_bt<0><<<dim3(3 * cD / 128, TOK / 128), 256, 0, stream>>>(
      h_b, wqkv_b, TOK, 3 * cD, cD, nullptr, nullptr, nullptr, q_b, k_b, v_b);
  attn_k<<<dim3(BH, cN / 64), 256, 0, stream>>>(q_b, k_b, v_b, keep, h_b);
  gemm_bt<1><<<dim3(cD / 128, TOK / 128), 256, 0, stream>>>(
      h_b, wproj_b, TOK, cD, cD, bproj, src, x1, nullptr, nullptr, nullptr);
  ln_k<1><<<TOK, 256, 0, stream>>>(x1, g1, be1, x_b, out);
  gemm_bt<2><<<dim3(cF / 128, TOK / 128), 256, 0, stream>>>(
      x_b, w1_b, TOK, cF, cD, b1, nullptr, nullptr, f1_b, nullptr, nullptr);
  gemm_bt<3><<<dim3(cD / 128, TOK / 128), 256, 0, stream>>>(
      f1_b, w2_b, TOK, cD, cF, b2, nullptr, out, nullptr, nullptr, nullptr);
}